// Round 9
// baseline (2298.951 us; speedup 1.0000x reference)
//
#include <hip/hip_runtime.h>
#include <stdint.h>

#define T_ROWS 1500000
#define N_ROWS 2000000
#define N_SEL  1048576
#define G_CNT  (N_SEL/4)
#define LB     (N_ROWS - N_SEL)
#define TILE   4096
#define NBLK   ((N_ROWS + TILE - 1)/TILE)     // 489
#define THREADS 512
#define WAVES  8
#define WTILE  (TILE/WAVES)                    // 512
#define WROUNDS (WTILE/64)                     // 8
#define BINS   256
#define NB_MX  ((T_ROWS + THREADS - 1)/THREADS)

static_assert((uint64_t)NBLK * TILE >= N_ROWS, "tile coverage");
static_assert(T_ROWS < (1 << 21), "tp fits 21 bits");
static_assert((LB * 4) % 16 == 0, "finalize uint4 alignment");
static_assert(N_ROWS < (1 << 27), "prefix fits 27-bit status value");

// code = (descending-orderable key << 32) | (flag!=0 << 21) | tp.
// LSD radix over bits [32,64) is stable -> ties keep original (index-ascending)
// order == jnp.argsort(-bt). Payload carries everything finalize needs.
// build fuses: codes + mxtab + GLOBAL 4-byte digit histogram (for digit bases).
__global__ __launch_bounds__(THREADS) void build_all(
        const float* __restrict__ nb, const float* __restrict__ td,
        uint64_t* __restrict__ codes, float* __restrict__ mxtab,
        uint32_t* __restrict__ gHist4) {
    const int b = blockIdx.x;
    if (b >= NBLK) {
        int i = (b - NBLK) * THREADS + threadIdx.x;
        if (i < T_ROWS) {
            float4 r = *(const float4*)(td + (size_t)i * 4);
            mxtab[i] = fmaxf(r.y, fmaxf(r.z, r.w));
        }
        return;
    }
    __shared__ uint32_t h[4 * BINS];
    const int t = threadIdx.x;
    const int lane = t & 63;
    #pragma unroll
    for (int k = t; k < 4 * BINS; k += THREADS) h[k] = 0;
    __syncthreads();
    const int base = b * TILE;
    #pragma unroll
    for (int r = 0; r < TILE / THREADS; ++r) {
        int i = base + r * THREADS + t;
        bool active = (i < N_ROWS);
        uint32_t kd = 0;
        if (active) {
            const float* row = nb + (size_t)i * 5;
            uint32_t u = __float_as_uint(row[1]);
            uint32_t ku = (u & 0x80000000u) ? ~u : (u | 0x80000000u); // asc uint == asc float
            kd = ~ku;                                                 // asc uint == desc float
            uint32_t tp = (uint32_t)(int)row[0];                      // exact: integral f32
            uint32_t fl = (row[4] != 0.0f) ? 1u : 0u;
            codes[i] = ((uint64_t)kd << 32) | (fl << 21) | tp;
            // bytes 0..2 are mantissa-ish (uniform): plain LDS atomics are cheap
            atomicAdd(&h[kd & 255u], 1u);
            atomicAdd(&h[256 + ((kd >> 8) & 255u)], 1u);
            atomicAdd(&h[512 + ((kd >> 16) & 255u)], 1u);
        }
        // byte 3 = sign+exponent (skewed): ballot-leader counting
        uint32_t d = kd >> 24;
        uint64_t m = __ballot(active ? 1 : 0);
        #pragma unroll
        for (int bb = 0; bb < 8; ++bb) {
            uint64_t x = __ballot((active && ((d >> bb) & 1u)) ? 1 : 0);
            m = ((d >> bb) & 1u) ? (m & x) : (m & ~x);
        }
        int ldr = __ffsll((unsigned long long)m) - 1;
        if (active && lane == ldr) atomicAdd(&h[768 + d], (uint32_t)__popcll(m));
    }
    __syncthreads();
    #pragma unroll
    for (int k = t; k < 4 * BINS; k += THREADS)
        if (h[k]) atomicAdd(&gHist4[k], h[k]);
}

// One-sweep scatter with decoupled lookback.
// gStat entry: [31:29]=epoch (1..4), [28:27]=state (1=AGG, 2=PREFIX), [26:0]=value.
// Stale entries (previous pass/call epoch, or 0xAA poison = epoch 5) read as invalid.
// SAFETY: lookback spins on predecessor blocks -> requires all NBLK blocks resident.
// LDS 41 KB -> 3 blocks/CU -> 768 >= 489 (2/CU = 512 also suffices).
template <int SHIFT, bool LAST>
__global__ __launch_bounds__(THREADS) void radix_scatter(
        const uint64_t* __restrict__ src, uint64_t* __restrict__ dst,
        uint32_t* __restrict__ dst32, const uint32_t* __restrict__ gHtot,
        uint32_t* __restrict__ gStat, uint32_t ep) {
    __shared__ uint64_t tileS[TILE];             // 32 KB
    __shared__ uint32_t cnt32[BINS * WAVES];     // 8 KB  per-(digit,wave) counts/cursors
    __shared__ uint32_t writeBase[BINS];
    __shared__ uint32_t wpT[WAVES], wpL[WAVES];

    const int t = threadIdx.x;
    const int lane = t & 63;
    const int w = t >> 6;
    const int blk = blockIdx.x;
    const int base = blk * TILE;
    const int tileCount = (N_ROWS - base < TILE) ? (N_ROWS - base) : TILE;

    // early issue: global digit totals (4 KB, L2-resident)
    uint32_t tot = (t < BINS) ? gHtot[t] : 0u;

    #pragma unroll
    for (int k = t; k < BINS * WAVES; k += THREADS) cnt32[k] = 0u;
    __syncthreads();

    // ---- phase A: per-wave digit counts via ballot match; save (rank,ldr,cnt) per round
    uint64_t creg[WROUNDS];
    uint32_t meta[WROUNDS];
    const uint64_t below = (lane == 0) ? 0ull : (~0ull >> (64 - lane));
    #pragma unroll
    for (int r = 0; r < WROUNDS; ++r) {
        int idx = base + w * WTILE + r * 64 + lane;
        bool active = (idx < N_ROWS);
        uint64_t c = active ? src[idx] : 0ull;
        creg[r] = c;
        uint32_t d = (uint32_t)(c >> SHIFT) & (BINS - 1);
        uint64_t m = __ballot(active ? 1 : 0);
        #pragma unroll
        for (int bb = 0; bb < 8; ++bb) {
            uint64_t x = __ballot((active && ((d >> bb) & 1u)) ? 1 : 0);
            m = ((d >> bb) & 1u) ? (m & x) : (m & ~x);
        }
        int ldr = __ffsll((unsigned long long)m) - 1;
        uint32_t cnt = (uint32_t)__popcll(m);
        uint32_t rank = (uint32_t)__popcll(m & below);
        meta[r] = rank | ((uint32_t)(ldr < 0 ? 0 : ldr) << 8) | (cnt << 16);
        if (active && lane == ldr)
            atomicAdd(&cnt32[d * WAVES + w], cnt);
    }
    __syncthreads();   // cnt32 complete

    // ---- decoupled lookback: publish AGG, walk predecessors, publish PREFIX
    uint32_t myCnt = 0, rp = 0;
    if (t < BINS) {
        #pragma unroll
        for (int wv = 0; wv < WAVES; ++wv) myCnt += cnt32[t * WAVES + wv];
        __hip_atomic_store(&gStat[(size_t)blk * BINS + t],
                           (ep << 29) | (1u << 27) | myCnt,
                           __ATOMIC_RELEASE, __HIP_MEMORY_SCOPE_AGENT);
        int j = blk - 1;
        while (j >= 0) {
            uint32_t s;
            do {
                s = __hip_atomic_load(&gStat[(size_t)j * BINS + t],
                                      __ATOMIC_ACQUIRE, __HIP_MEMORY_SCOPE_AGENT);
            } while ((s >> 29) != ep);
            rp += s & 0x07FFFFFFu;
            if (s & (2u << 27)) break;   // PREFIX: done
            --j;                         // AGG: keep walking
        }
        __hip_atomic_store(&gStat[(size_t)blk * BINS + t],
                           (ep << 29) | (2u << 27) | (rp + myCnt),
                           __ATOMIC_RELEASE, __HIP_MEMORY_SCOPE_AGENT);
    }

    // ---- phase B1: dual block-exclusive scans over digits (tot -> exT, myCnt -> exL)
    uint32_t sT = tot, sL = myCnt;
    #pragma unroll
    for (int off = 1; off < 64; off <<= 1) {
        uint32_t aT = __shfl_up(sT, off, 64);
        uint32_t aL = __shfl_up(sL, off, 64);
        if (lane >= off) { sT += aT; sL += aL; }
    }
    if (lane == 63) { wpT[w] = sT; wpL[w] = sL; }
    __syncthreads();
    uint32_t exT = sT - tot, exL = sL - myCnt;
    #pragma unroll
    for (int wv = 0; wv < WAVES; ++wv) if (wv < w) { exT += wpT[wv]; exL += wpL[wv]; }

    // ---- phase B2: writeBase + per-wave cursors (thread t owns digit t exclusively)
    if (t < BINS) {
        writeBase[t] = exT + rp - exL;
        uint32_t run = exL;
        #pragma unroll
        for (int wv = 0; wv < WAVES; ++wv) {
            uint32_t c0 = cnt32[t * WAVES + wv];
            cnt32[t * WAVES + wv] = run;
            run += c0;
        }
    }
    __syncthreads();

    // ---- phase C: ballot-free — leader atomicAdd on cursor, shfl, LDS scatter
    #pragma unroll
    for (int r = 0; r < WROUNDS; ++r) {
        int idx = base + w * WTILE + r * 64 + lane;
        bool active = (idx < N_ROWS);
        uint64_t c = creg[r];
        uint32_t d = (uint32_t)(c >> SHIFT) & (BINS - 1);
        uint32_t mt = meta[r];
        uint32_t rank = mt & 0xFFu;
        int ldr = (int)((mt >> 8) & 0xFFu);
        uint32_t cnt = mt >> 16;
        uint32_t before = 0;
        if (active && lane == ldr)
            before = atomicAdd(&cnt32[d * WAVES + w], cnt);
        before = __shfl(before, ldr, 64);
        if (active) tileS[before + rank] = c;
    }
    __syncthreads();

    // ---- write-out: consecutive sorted positions share digit -> 128B avg segments
    #pragma unroll
    for (int r = 0; r < TILE / THREADS; ++r) {
        int p = r * THREADS + t;
        if (p < tileCount) {
            uint64_t c = tileS[p];
            uint32_t d = (uint32_t)(c >> SHIFT) & (BINS - 1);
            uint32_t g = writeBase[d] + p;
            if (!LAST) {
                dst[(size_t)g] = c;
            } else if (g >= LB) {        // only selected range is read; payload only
                dst32[g] = (uint32_t)c;
            }
        }
    }
}

__global__ void finalize(const uint32_t* __restrict__ pay, const float* __restrict__ td,
                         const float* __restrict__ mxtab, float* __restrict__ out) {
    int g = blockIdx.x * 256 + threadIdx.x;
    if (g >= G_CNT) return;
    uint4 p4 = *(const uint4*)(pay + LB + (size_t)g * 4);
    uint32_t cs[4] = {p4.x, p4.y, p4.z, p4.w};
    float maxmin = -100000.0f;
    int maxindex = -100;
    #pragma unroll
    for (int j = 0; j < 4; ++j) {
        int tp = (int)(cs[j] & 0x1FFFFFu);
        bool re1 = ((cs[j] >> 21) & 1u) != 0u;
        float mx = mxtab[tp];
        bool gt = (mx > maxmin);
        if (re1 == gt) { maxmin = mx; maxindex = tp; }
    }
    int mi = maxindex < 0 ? 0 : maxindex;   // clip lower bound; upper never binds
    float4 row = *(const float4*)(td + (size_t)mi * 4);
    *(float4*)(out + (size_t)g * 4) = row;
}

extern "C" void kernel_launch(void* const* d_in, const int* in_sizes, int n_in,
                              void* d_out, int out_size, void* d_ws, size_t ws_size,
                              hipStream_t stream) {
    const float* td = (const float*)d_in[0];
    const float* nb = (const float*)d_in[1];
    float* out = (float*)d_out;
    uint8_t* ws = (uint8_t*)d_ws;

    // layout: mxtab 6MB | gHist4 4KB | gStat 489*256*4 ~489KB | A 16MB | B 16MB
    float*    mxtab  = (float*)(ws);
    uint32_t* gHist4 = (uint32_t*)(ws + (size_t)6 * 1024 * 1024);
    uint32_t* gStat  = (uint32_t*)(ws + (size_t)6 * 1024 * 1024 + 4096);
    uint64_t* A      = (uint64_t*)(ws + (size_t)8 * 1024 * 1024);
    uint64_t* B      = (uint64_t*)(ws + (size_t)24 * 1024 * 1024);

    // zero gHist4 + gStat (epoch scheme handles pass-to-pass staleness; this kills
    // first-call garbage that could alias a valid epoch)
    hipMemsetAsync(gHist4, 0, 4096 + (size_t)NBLK * BINS * 4, stream);

    build_all<<<NBLK + NB_MX, THREADS, 0, stream>>>(nb, td, A, mxtab, gHist4);

    radix_scatter<32, false><<<NBLK, THREADS, 0, stream>>>(A, B, nullptr, gHist4 + 0,   gStat, 1u);
    radix_scatter<40, false><<<NBLK, THREADS, 0, stream>>>(B, A, nullptr, gHist4 + 256, gStat, 2u);
    radix_scatter<48, false><<<NBLK, THREADS, 0, stream>>>(A, B, nullptr, gHist4 + 512, gStat, 3u);
    radix_scatter<56, true ><<<NBLK, THREADS, 0, stream>>>(B, nullptr, (uint32_t*)A, gHist4 + 768, gStat, 4u);

    finalize<<<(G_CNT + 255) / 256, 256, 0, stream>>>((const uint32_t*)A, td, mxtab, out);
}

// Round 10
// 170.730 us; speedup vs baseline: 13.4654x; 13.4654x over previous
//
#include <hip/hip_runtime.h>
#include <stdint.h>

#define T_ROWS 1500000
#define N_ROWS 2000000
#define N_SEL  1048576
#define G_CNT  (N_SEL/4)
#define LB     (N_ROWS - N_SEL)
#define TILE   4096
#define NBLK   ((N_ROWS + TILE - 1)/TILE)     // 489
#define NBLK1  (NBLK + 1)                      // 490 (row stride; last col = total)
#define THREADS 512
#define WAVES  8
#define WTILE  (TILE/WAVES)                    // 512
#define WROUNDS (WTILE/64)                     // 8
#define BINS   256
#define NB_MX  ((T_ROWS + THREADS - 1)/THREADS)

static_assert((uint64_t)NBLK * TILE >= N_ROWS, "tile coverage");
static_assert(T_ROWS < (1 << 21), "tp fits 21 bits");
static_assert((LB * 4) % 16 == 0, "finalize uint4 alignment");
static_assert(3 * 256 >= NBLK, "all blocks co-resident (spin safety)");

// code = (descending-orderable key << 32) | (flag!=0 << 21) | tp.
// LSD radix over bits [32,64) is stable -> ties keep original (index-ascending)
// order == jnp.argsort(-bt). Payload carries everything finalize needs.
// build fuses: codes + mxtab + pass-0 per-tile histogram + done-counter zero.
__global__ __launch_bounds__(THREADS) void build_all(
        const float* __restrict__ nb, const float* __restrict__ td,
        uint64_t* __restrict__ codes, float* __restrict__ mxtab,
        uint32_t* __restrict__ gH, uint32_t* __restrict__ done) {
    const int b = blockIdx.x;
    if (b >= NBLK) {
        if (b == NBLK && threadIdx.x == 0)
            __hip_atomic_store(done, 0u, __ATOMIC_RELAXED, __HIP_MEMORY_SCOPE_AGENT);
        int i = (b - NBLK) * THREADS + threadIdx.x;
        if (i < T_ROWS) {
            float4 r = *(const float4*)(td + (size_t)i * 4);
            mxtab[i] = fmaxf(r.y, fmaxf(r.z, r.w));
        }
        return;
    }
    __shared__ uint32_t h[BINS];
    const int t = threadIdx.x;
    if (t < BINS) h[t] = 0;
    __syncthreads();
    const int base = b * TILE;
    #pragma unroll
    for (int r = 0; r < TILE / THREADS; ++r) {
        int i = base + r * THREADS + t;
        if (i < N_ROWS) {
            const float* row = nb + (size_t)i * 5;
            uint32_t u = __float_as_uint(row[1]);
            uint32_t ku = (u & 0x80000000u) ? ~u : (u | 0x80000000u); // asc uint == asc float
            uint32_t kd = ~ku;                                        // asc uint == desc float
            uint32_t tp = (uint32_t)(int)row[0];                      // exact: integral f32
            uint32_t fl = (row[4] != 0.0f) ? 1u : 0u;
            codes[i] = ((uint64_t)kd << 32) | (fl << 21) | tp;
            // pass-0 digit = low mantissa byte (uniform) -> plain atomics cheap
            atomicAdd(&h[kd & (BINS - 1)], 1u);
        }
    }
    __syncthreads();
    if (t < BINS) gH[(size_t)t * NBLK1 + b] = h[t];
}

// Uniform-digit histogram (mantissa bytes): plain LDS atomics, u32 loads only.
template <int SHIFT32>
__global__ __launch_bounds__(THREADS) void radix_hist_u(
        const uint64_t* __restrict__ src, uint32_t* __restrict__ gH) {
    __shared__ uint32_t h[BINS];
    const int t = threadIdx.x;
    if (t < BINS) h[t] = 0;
    __syncthreads();
    const int base = blockIdx.x * TILE;
    const uint32_t* s32 = (const uint32_t*)src;
    #pragma unroll
    for (int r = 0; r < TILE / THREADS; ++r) {
        int i = base + r * THREADS + t;
        if (i < N_ROWS)
            atomicAdd(&h[(s32[2 * (size_t)i + 1] >> SHIFT32) & (BINS - 1)], 1u);
    }
    __syncthreads();
    if (t < BINS) gH[(size_t)t * NBLK1 + blockIdx.x] = h[t];
}

// Skewed-digit histogram (top byte: sign+exponent): ballot-leader counting.
template <int SHIFT32>
__global__ __launch_bounds__(THREADS) void radix_hist_s(
        const uint64_t* __restrict__ src, uint32_t* __restrict__ gH) {
    __shared__ uint32_t h[BINS];
    const int t = threadIdx.x;
    const int lane = t & 63;
    if (t < BINS) h[t] = 0;
    __syncthreads();
    const int base = blockIdx.x * TILE;
    const uint32_t* s32 = (const uint32_t*)src;
    #pragma unroll
    for (int r = 0; r < TILE / THREADS; ++r) {
        int i = base + r * THREADS + t;
        bool active = (i < N_ROWS);
        uint32_t d = 0;
        if (active) d = (s32[2 * (size_t)i + 1] >> SHIFT32) & (BINS - 1);
        uint64_t m = __ballot(active ? 1 : 0);
        #pragma unroll
        for (int bb = 0; bb < 8; ++bb) {
            uint64_t x = __ballot((active && ((d >> bb) & 1u)) ? 1 : 0);
            m = ((d >> bb) & 1u) ? (m & x) : (m & ~x);
        }
        int ldr = __ffsll((unsigned long long)m) - 1;
        if (active && lane == ldr) atomicAdd(&h[d], (uint32_t)__popcll(m));
    }
    __syncthreads();
    if (t < BINS) gH[(size_t)t * NBLK1 + blockIdx.x] = h[t];
}

// Scatter with FUSED row-scan: blocks 0..255 (wave 0) scan digit-row blk in place
// and bump `done` (release). Phase B waits for done >= target (acquire spin on one
// counter, ~0 iterations expected since phase A >> scan time). All 489 blocks are
// co-resident (LDS 42.5KB -> 3/CU -> 768 slots), so no launch-order deadlock.
template <int SHIFT, bool LAST>
__global__ __launch_bounds__(THREADS) void radix_scatter(
        const uint64_t* __restrict__ src, uint64_t* __restrict__ dst,
        uint32_t* __restrict__ dst32, uint32_t* __restrict__ gH,
        uint32_t* __restrict__ done, uint32_t target) {
    __shared__ uint64_t tileS[TILE];             // 32 KB
    __shared__ uint32_t cnt32[BINS * WAVES];     // 8 KB  per-(digit,wave) counts/cursors
    __shared__ uint32_t writeBase[BINS];
    __shared__ uint32_t wpT[WAVES], wpL[WAVES];

    const int t = threadIdx.x;
    const int lane = t & 63;
    const int w = t >> 6;
    const int blk = blockIdx.x;
    const int base = blk * TILE;
    const int tileCount = (N_ROWS - base < TILE) ? (N_ROWS - base) : TILE;

    #pragma unroll
    for (int k = t; k < BINS * WAVES; k += THREADS) cnt32[k] = 0u;
    __syncthreads();

    // ---- fused scan (blocks 0..255, wave 0 only): exclusive scan of digit-row blk
    if (blk < BINS && w == 0) {
        uint32_t* row = gH + (size_t)blk * NBLK1;
        uint32_t carry = 0;
        for (int b0 = 0; b0 < NBLK; b0 += 64) {
            int i = b0 + lane;
            uint32_t v = (i < NBLK) ? row[i] : 0u;
            uint32_t s = v;
            #pragma unroll
            for (int off = 1; off < 64; off <<= 1) {
                uint32_t a = __shfl_up(s, off, 64);
                if (lane >= off) s += a;
            }
            if (i < NBLK)
                __hip_atomic_store(&row[i], s - v + carry,
                                   __ATOMIC_RELAXED, __HIP_MEMORY_SCOPE_AGENT);
            carry += __shfl(s, 63, 64);
        }
        if (lane == 0) {
            __hip_atomic_store(&row[NBLK], carry,
                               __ATOMIC_RELAXED, __HIP_MEMORY_SCOPE_AGENT);
            __hip_atomic_fetch_add(done, 1u,
                                   __ATOMIC_RELEASE, __HIP_MEMORY_SCOPE_AGENT);
        }
    }

    // ---- phase A: per-wave digit counts via ballot match; save (rank,ldr,cnt) per round
    uint64_t creg[WROUNDS];
    uint32_t meta[WROUNDS];
    const uint64_t below = (lane == 0) ? 0ull : (~0ull >> (64 - lane));
    #pragma unroll
    for (int r = 0; r < WROUNDS; ++r) {
        int idx = base + w * WTILE + r * 64 + lane;
        bool active = (idx < N_ROWS);
        uint64_t c = active ? src[idx] : 0ull;
        creg[r] = c;
        uint32_t d = (uint32_t)(c >> SHIFT) & (BINS - 1);
        uint64_t m = __ballot(active ? 1 : 0);
        #pragma unroll
        for (int bb = 0; bb < 8; ++bb) {
            uint64_t x = __ballot((active && ((d >> bb) & 1u)) ? 1 : 0);
            m = ((d >> bb) & 1u) ? (m & x) : (m & ~x);
        }
        int ldr = __ffsll((unsigned long long)m) - 1;
        uint32_t cnt = (uint32_t)__popcll(m);
        uint32_t rank = (uint32_t)__popcll(m & below);
        meta[r] = rank | ((uint32_t)(ldr < 0 ? 0 : ldr) << 8) | (cnt << 16);
        if (active && lane == ldr)
            atomicAdd(&cnt32[d * WAVES + w], cnt);
    }
    __syncthreads();   // cnt32 complete

    // ---- wait for all 256 scan rows of this pass (usually already done)
    if (t == 0) {
        while (__hip_atomic_load(done, __ATOMIC_ACQUIRE, __HIP_MEMORY_SCOPE_AGENT) < target) {}
    }
    __syncthreads();

    // ---- phase B0: per-digit prefix values from scanned gH (coherent-path loads)
    uint32_t rp = 0, lc = 0, tot = 0;
    if (t < BINS) {
        uint32_t* row = gH + (size_t)t * NBLK1;
        rp  = __hip_atomic_load(&row[blk], __ATOMIC_RELAXED, __HIP_MEMORY_SCOPE_AGENT);
        uint32_t nxt = __hip_atomic_load(&row[blk + 1], __ATOMIC_RELAXED, __HIP_MEMORY_SCOPE_AGENT);
        tot = __hip_atomic_load(&row[NBLK], __ATOMIC_RELAXED, __HIP_MEMORY_SCOPE_AGENT);
        lc = nxt - rp;
    }

    // ---- phase B1: dual block-exclusive scans over digits (tot -> exT, lc -> exL)
    uint32_t sT = tot, sL = lc;
    #pragma unroll
    for (int off = 1; off < 64; off <<= 1) {
        uint32_t aT = __shfl_up(sT, off, 64);
        uint32_t aL = __shfl_up(sL, off, 64);
        if (lane >= off) { sT += aT; sL += aL; }
    }
    if (lane == 63) { wpT[w] = sT; wpL[w] = sL; }
    __syncthreads();
    uint32_t exT = sT - tot, exL = sL - lc;
    #pragma unroll
    for (int wv = 0; wv < WAVES; ++wv) if (wv < w) { exT += wpT[wv]; exL += wpL[wv]; }

    // ---- phase B2: writeBase + per-wave cursors (thread t owns digit t exclusively)
    if (t < BINS) {
        writeBase[t] = exT + rp - exL;
        uint32_t run = exL;
        #pragma unroll
        for (int wv = 0; wv < WAVES; ++wv) {
            uint32_t c0 = cnt32[t * WAVES + wv];
            cnt32[t * WAVES + wv] = run;
            run += c0;
        }
    }
    __syncthreads();

    // ---- phase C: ballot-free — leader atomicAdd on cursor, shfl, LDS scatter
    #pragma unroll
    for (int r = 0; r < WROUNDS; ++r) {
        int idx = base + w * WTILE + r * 64 + lane;
        bool active = (idx < N_ROWS);
        uint64_t c = creg[r];
        uint32_t d = (uint32_t)(c >> SHIFT) & (BINS - 1);
        uint32_t mt = meta[r];
        uint32_t rank = mt & 0xFFu;
        int ldr = (int)((mt >> 8) & 0xFFu);
        uint32_t cnt = mt >> 16;
        uint32_t before = 0;
        if (active && lane == ldr)
            before = atomicAdd(&cnt32[d * WAVES + w], cnt);
        before = __shfl(before, ldr, 64);
        if (active) tileS[before + rank] = c;
    }
    __syncthreads();

    // ---- write-out: consecutive sorted positions share digit -> 128B avg segments
    #pragma unroll
    for (int r = 0; r < TILE / THREADS; ++r) {
        int p = r * THREADS + t;
        if (p < tileCount) {
            uint64_t c = tileS[p];
            uint32_t d = (uint32_t)(c >> SHIFT) & (BINS - 1);
            uint32_t g = writeBase[d] + p;
            if (!LAST) {
                dst[(size_t)g] = c;
            } else if (g >= LB) {        // only selected range is read; payload only
                dst32[g] = (uint32_t)c;
            }
        }
    }
}

__global__ void finalize(const uint32_t* __restrict__ pay, const float* __restrict__ td,
                         const float* __restrict__ mxtab, float* __restrict__ out) {
    int g = blockIdx.x * 256 + threadIdx.x;
    if (g >= G_CNT) return;
    uint4 p4 = *(const uint4*)(pay + LB + (size_t)g * 4);
    uint32_t cs[4] = {p4.x, p4.y, p4.z, p4.w};
    float maxmin = -100000.0f;
    int maxindex = -100;
    #pragma unroll
    for (int j = 0; j < 4; ++j) {
        int tp = (int)(cs[j] & 0x1FFFFFu);
        bool re1 = ((cs[j] >> 21) & 1u) != 0u;
        float mx = mxtab[tp];
        bool gt = (mx > maxmin);
        if (re1 == gt) { maxmin = mx; maxindex = tp; }
    }
    int mi = maxindex < 0 ? 0 : maxindex;   // clip lower bound; upper never binds
    float4 row = *(const float4*)(td + (size_t)mi * 4);
    *(float4*)(out + (size_t)g * 4) = row;
}

extern "C" void kernel_launch(void* const* d_in, const int* in_sizes, int n_in,
                              void* d_out, int out_size, void* d_ws, size_t ws_size,
                              hipStream_t stream) {
    const float* td = (const float*)d_in[0];
    const float* nb = (const float*)d_in[1];
    float* out = (float*)d_out;
    uint8_t* ws = (uint8_t*)d_ws;

    // layout: mxtab 6MB | gH 256*490*4 ~490KB | done 4B | A @8MB | B @24MB (~40MB)
    float*    mxtab = (float*)(ws);
    uint32_t* gH    = (uint32_t*)(ws + (size_t)6 * 1024 * 1024);
    uint32_t* done  = (uint32_t*)(ws + (size_t)6 * 1024 * 1024 + 512 * 1024);
    uint64_t* A     = (uint64_t*)(ws + (size_t)8 * 1024 * 1024);
    uint64_t* B     = (uint64_t*)(ws + (size_t)24 * 1024 * 1024);

    build_all<<<NBLK + NB_MX, THREADS, 0, stream>>>(nb, td, A, mxtab, gH, done);

    // pass 0: code bits [32,40) — hist fused into build; scan fused into scatter
    radix_scatter<32, false><<<NBLK, THREADS, 0, stream>>>(A, B, nullptr, gH, done, 256u);

    // pass 1: bits [40,48) — uniform digit
    radix_hist_u<8><<<NBLK, THREADS, 0, stream>>>(B, gH);
    radix_scatter<40, false><<<NBLK, THREADS, 0, stream>>>(B, A, nullptr, gH, done, 512u);

    // pass 2: bits [48,56) — uniform digit
    radix_hist_u<16><<<NBLK, THREADS, 0, stream>>>(A, gH);
    radix_scatter<48, false><<<NBLK, THREADS, 0, stream>>>(A, B, nullptr, gH, done, 768u);

    // pass 3: bits [56,64) — skewed digit; slim payload-only writes in selected range
    radix_hist_s<24><<<NBLK, THREADS, 0, stream>>>(B, gH);
    radix_scatter<56, true><<<NBLK, THREADS, 0, stream>>>(B, nullptr, (uint32_t*)A, gH, done, 1024u);

    finalize<<<(G_CNT + 255) / 256, 256, 0, stream>>>((const uint32_t*)A, td, mxtab, out);
}

// Round 11
// 131.706 us; speedup vs baseline: 17.4551x; 1.2963x over previous
//
#include <hip/hip_runtime.h>
#include <stdint.h>

#define T_ROWS 1500000
#define N_ROWS 2000000
#define N_SEL  1048576
#define G_CNT  (N_SEL/4)
#define LB     (N_ROWS - N_SEL)
#define TILE   4096
#define NBLK   ((N_ROWS + TILE - 1)/TILE)     // 489
#define NBLK1  (NBLK + 1)                      // 490 (row stride; last col = total)
#define STHREADS 1024                          // scatter block (16 waves)
#define SWAVES 16
#define WTILE  (TILE/SWAVES)                   // 256
#define WROUNDS (WTILE/64)                     // 4
#define HTHREADS 512
#define BINS   256
#define NB_MX  ((T_ROWS + HTHREADS - 1)/HTHREADS)

static_assert((uint64_t)NBLK * TILE >= N_ROWS, "tile coverage");
static_assert(T_ROWS < (1 << 21), "tp fits 21 bits");
static_assert((LB * 4) % 16 == 0, "finalize uint4 alignment");

// code = (descending-orderable key << 32) | (flag!=0 << 21) | tp.
// LSD radix over bits [32,64) is stable -> ties keep original (index-ascending)
// order == jnp.argsort(-bt). Payload carries everything finalize needs.
// build fuses codes + mxtab + pass-0 per-tile histogram (plain atomics: low
// mantissa byte is uniform).
__global__ __launch_bounds__(HTHREADS) void build_all(
        const float* __restrict__ nb, const float* __restrict__ td,
        uint64_t* __restrict__ codes, float* __restrict__ mxtab,
        uint32_t* __restrict__ gH) {
    const int b = blockIdx.x;
    if (b >= NBLK) {
        int i = (b - NBLK) * HTHREADS + threadIdx.x;
        if (i < T_ROWS) {
            float4 r = *(const float4*)(td + (size_t)i * 4);
            mxtab[i] = fmaxf(r.y, fmaxf(r.z, r.w));
        }
        return;
    }
    __shared__ uint32_t h[BINS];
    const int t = threadIdx.x;
    if (t < BINS) h[t] = 0;
    __syncthreads();
    const int base = b * TILE;
    #pragma unroll
    for (int r = 0; r < TILE / HTHREADS; ++r) {
        int i = base + r * HTHREADS + t;
        if (i < N_ROWS) {
            const float* row = nb + (size_t)i * 5;
            uint32_t u = __float_as_uint(row[1]);
            uint32_t ku = (u & 0x80000000u) ? ~u : (u | 0x80000000u); // asc uint == asc float
            uint32_t kd = ~ku;                                        // asc uint == desc float
            uint32_t tp = (uint32_t)(int)row[0];                      // exact: integral f32
            uint32_t fl = (row[4] != 0.0f) ? 1u : 0u;
            codes[i] = ((uint64_t)kd << 32) | (fl << 21) | tp;
            atomicAdd(&h[kd & (BINS - 1)], 1u);   // uniform byte: plain atomics cheap
        }
    }
    __syncthreads();
    if (t < BINS) gH[(size_t)t * NBLK1 + b] = h[t];
}

// Uniform-digit histogram (mantissa bytes): uint4 loads (2 keys), plain LDS atomics.
template <int SHIFT32>
__global__ __launch_bounds__(HTHREADS) void radix_hist_u(
        const uint64_t* __restrict__ src, uint32_t* __restrict__ gH) {
    __shared__ uint32_t h[BINS];
    const int t = threadIdx.x;
    if (t < BINS) h[t] = 0;
    __syncthreads();
    const uint4* s4 = (const uint4*)(src + (size_t)blockIdx.x * TILE);
    const int pairBase = blockIdx.x * (TILE / 2);
    #pragma unroll
    for (int r = 0; r < TILE / (2 * HTHREADS); ++r) {
        int j = r * HTHREADS + t;                 // pair index within tile
        uint4 v = s4[j];                          // keys 2j, 2j+1 (alloc covers pad)
        int i0 = (pairBase + j) * 2;
        if (i0 < N_ROWS)     atomicAdd(&h[(v.y >> SHIFT32) & (BINS - 1)], 1u);
        if (i0 + 1 < N_ROWS) atomicAdd(&h[(v.w >> SHIFT32) & (BINS - 1)], 1u);
    }
    __syncthreads();
    if (t < BINS) gH[(size_t)t * NBLK1 + blockIdx.x] = h[t];
}

// Skewed-digit histogram (top byte: sign+exponent): ballot-leader counting.
template <int SHIFT32>
__global__ __launch_bounds__(HTHREADS) void radix_hist_s(
        const uint64_t* __restrict__ src, uint32_t* __restrict__ gH) {
    __shared__ uint32_t h[BINS];
    const int t = threadIdx.x;
    const int lane = t & 63;
    if (t < BINS) h[t] = 0;
    __syncthreads();
    const int base = blockIdx.x * TILE;
    const uint32_t* s32 = (const uint32_t*)src;
    #pragma unroll
    for (int r = 0; r < TILE / HTHREADS; ++r) {
        int i = base + r * HTHREADS + t;
        bool active = (i < N_ROWS);
        uint32_t d = 0;
        if (active) d = (s32[2 * (size_t)i + 1] >> SHIFT32) & (BINS - 1);
        uint64_t m = __ballot(active ? 1 : 0);
        #pragma unroll
        for (int bb = 0; bb < 8; ++bb) {
            uint64_t x = __ballot((active && ((d >> bb) & 1u)) ? 1 : 0);
            m = ((d >> bb) & 1u) ? (m & x) : (m & ~x);
        }
        int ldr = __ffsll((unsigned long long)m) - 1;
        if (active && lane == ldr) atomicAdd(&h[d], (uint32_t)__popcll(m));
    }
    __syncthreads();
    if (t < BINS) gH[(size_t)t * NBLK1 + blockIdx.x] = h[t];
}

// one block per digit: exclusive scan of contiguous row; total -> row[NBLK] and col NBLK
__global__ void radix_rowscan(uint32_t* __restrict__ gH) {
    const int d = blockIdx.x;
    const int lane = threadIdx.x;
    uint32_t* row = gH + (size_t)d * NBLK1;
    uint32_t carry = 0;
    for (int b0 = 0; b0 < NBLK; b0 += 64) {
        int i = b0 + lane;
        uint32_t v = (i < NBLK) ? row[i] : 0u;
        uint32_t s = v;
        #pragma unroll
        for (int off = 1; off < 64; off <<= 1) {
            uint32_t tt = __shfl_up(s, off, 64);
            if (lane >= off) s += tt;
        }
        if (i < NBLK) row[i] = s - v + carry;
        carry += __shfl(s, 63, 64);
    }
    if (lane == 0) row[NBLK] = carry;
}

// 16-wave scatter. cnt32 layout [wave][digit] -> LDS-bank-conflict-free leader
// atomics (old [digit][wave] put fixed-wave atomics on 4 of 32 banks).
template <int SHIFT, bool LAST>
__global__ __launch_bounds__(STHREADS) void radix_scatter(
        const uint64_t* __restrict__ src, uint64_t* __restrict__ dst,
        uint32_t* __restrict__ dst32, const uint32_t* __restrict__ gH) {
    __shared__ uint64_t tileS[TILE];              // 32 KB
    __shared__ uint32_t cnt32[SWAVES * BINS];     // 16 KB [wave][digit]
    __shared__ uint32_t writeBase[BINS];
    __shared__ uint32_t wpT[SWAVES], wpL[SWAVES];

    const int t = threadIdx.x;
    const int lane = t & 63;
    const int w = t >> 6;
    const int blk = blockIdx.x;
    const int base = blk * TILE;
    const int tileCount = (N_ROWS - base < TILE) ? (N_ROWS - base) : TILE;

    // early issue: this block's prefix data (scanned rows, plain cached loads)
    uint32_t rp = 0, lc = 0, tot = 0;
    if (t < BINS) {
        const uint32_t* row = gH + (size_t)t * NBLK1;
        rp = row[blk];
        lc = row[blk + 1] - rp;
        tot = row[NBLK];
    }

    #pragma unroll
    for (int k = t; k < SWAVES * BINS; k += STHREADS) cnt32[k] = 0u;
    __syncthreads();

    // ---- phase A: per-wave digit counts via ballot match; save (rank,ldr,cnt)/round
    uint64_t creg[WROUNDS];
    uint32_t meta[WROUNDS];
    const uint64_t below = (lane == 0) ? 0ull : (~0ull >> (64 - lane));
    #pragma unroll
    for (int r = 0; r < WROUNDS; ++r) {
        int idx = base + w * WTILE + r * 64 + lane;
        bool active = (idx < N_ROWS);
        uint64_t c = active ? src[idx] : 0ull;
        creg[r] = c;
        uint32_t d = (uint32_t)(c >> SHIFT) & (BINS - 1);
        uint64_t m = __ballot(active ? 1 : 0);
        #pragma unroll
        for (int bb = 0; bb < 8; ++bb) {
            uint64_t x = __ballot((active && ((d >> bb) & 1u)) ? 1 : 0);
            m = ((d >> bb) & 1u) ? (m & x) : (m & ~x);
        }
        int ldr = __ffsll((unsigned long long)m) - 1;
        uint32_t cnt = (uint32_t)__popcll(m);
        uint32_t rank = (uint32_t)__popcll(m & below);
        meta[r] = rank | ((uint32_t)(ldr < 0 ? 0 : ldr) << 8) | (cnt << 16);
        if (active && lane == ldr)
            atomicAdd(&cnt32[w * BINS + d], cnt);
    }
    __syncthreads();   // cnt32 complete

    // ---- phase B1: dual block-exclusive scans over digits (tot -> exT, lc -> exL)
    uint32_t sT = tot, sL = lc;
    #pragma unroll
    for (int off = 1; off < 64; off <<= 1) {
        uint32_t aT = __shfl_up(sT, off, 64);
        uint32_t aL = __shfl_up(sL, off, 64);
        if (lane >= off) { sT += aT; sL += aL; }
    }
    if (lane == 63) { wpT[w] = sT; wpL[w] = sL; }
    __syncthreads();
    uint32_t exT = sT - tot, exL = sL - lc;
    #pragma unroll
    for (int wv = 0; wv < SWAVES; ++wv) if (wv < w) { exT += wpT[wv]; exL += wpL[wv]; }

    // ---- phase B2: writeBase + per-wave cursors (thread t owns digit t)
    if (t < BINS) {
        writeBase[t] = exT + rp - exL;
        uint32_t run = exL;
        #pragma unroll
        for (int wv = 0; wv < SWAVES; ++wv) {
            uint32_t c0 = cnt32[wv * BINS + t];
            cnt32[wv * BINS + t] = run;
            run += c0;
        }
    }
    __syncthreads();

    // ---- phase C: ballot-free — leader atomicAdd on cursor, shfl, LDS scatter
    #pragma unroll
    for (int r = 0; r < WROUNDS; ++r) {
        int idx = base + w * WTILE + r * 64 + lane;
        bool active = (idx < N_ROWS);
        uint64_t c = creg[r];
        uint32_t d = (uint32_t)(c >> SHIFT) & (BINS - 1);
        uint32_t mt = meta[r];
        uint32_t rank = mt & 0xFFu;
        int ldr = (int)((mt >> 8) & 0xFFu);
        uint32_t cnt = mt >> 16;
        uint32_t before = 0;
        if (active && lane == ldr)
            before = atomicAdd(&cnt32[w * BINS + d], cnt);
        before = __shfl(before, ldr, 64);
        if (active) tileS[before + rank] = c;
    }
    __syncthreads();

    // ---- write-out: consecutive sorted positions share digit -> 128B avg segments
    #pragma unroll
    for (int r = 0; r < TILE / STHREADS; ++r) {
        int p = r * STHREADS + t;
        if (p < tileCount) {
            uint64_t c = tileS[p];
            uint32_t d = (uint32_t)(c >> SHIFT) & (BINS - 1);
            uint32_t g = writeBase[d] + p;
            if (!LAST) {
                dst[(size_t)g] = c;
            } else if (g >= LB) {        // only selected range is read; payload only
                dst32[g] = (uint32_t)c;
            }
        }
    }
}

__global__ void finalize(const uint32_t* __restrict__ pay, const float* __restrict__ td,
                         const float* __restrict__ mxtab, float* __restrict__ out) {
    int g = blockIdx.x * 256 + threadIdx.x;
    if (g >= G_CNT) return;
    uint4 p4 = *(const uint4*)(pay + LB + (size_t)g * 4);
    uint32_t cs[4] = {p4.x, p4.y, p4.z, p4.w};
    float maxmin = -100000.0f;
    int maxindex = -100;
    #pragma unroll
    for (int j = 0; j < 4; ++j) {
        int tp = (int)(cs[j] & 0x1FFFFFu);
        bool re1 = ((cs[j] >> 21) & 1u) != 0u;
        float mx = mxtab[tp];
        bool gt = (mx > maxmin);
        if (re1 == gt) { maxmin = mx; maxindex = tp; }
    }
    int mi = maxindex < 0 ? 0 : maxindex;   // clip lower bound; upper never binds
    float4 row = *(const float4*)(td + (size_t)mi * 4);
    *(float4*)(out + (size_t)g * 4) = row;
}

extern "C" void kernel_launch(void* const* d_in, const int* in_sizes, int n_in,
                              void* d_out, int out_size, void* d_ws, size_t ws_size,
                              hipStream_t stream) {
    const float* td = (const float*)d_in[0];
    const float* nb = (const float*)d_in[1];
    float* out = (float*)d_out;
    uint8_t* ws = (uint8_t*)d_ws;

    // layout: mxtab 6MB | gH 256*490*4 ~490KB | A @8MB | B @24MB (~40MB)
    float*    mxtab = (float*)(ws);
    uint32_t* gH    = (uint32_t*)(ws + (size_t)6 * 1024 * 1024);
    uint64_t* A     = (uint64_t*)(ws + (size_t)8 * 1024 * 1024);
    uint64_t* B     = (uint64_t*)(ws + (size_t)24 * 1024 * 1024);

    build_all<<<NBLK + NB_MX, HTHREADS, 0, stream>>>(nb, td, A, mxtab, gH);

    // pass 0: code bits [32,40) — histogram fused into build
    radix_rowscan<<<BINS, 64, 0, stream>>>(gH);
    radix_scatter<32, false><<<NBLK, STHREADS, 0, stream>>>(A, B, nullptr, gH);

    // pass 1: bits [40,48) — uniform digit
    radix_hist_u<8><<<NBLK, HTHREADS, 0, stream>>>(B, gH);
    radix_rowscan<<<BINS, 64, 0, stream>>>(gH);
    radix_scatter<40, false><<<NBLK, STHREADS, 0, stream>>>(B, A, nullptr, gH);

    // pass 2: bits [48,56) — uniform digit
    radix_hist_u<16><<<NBLK, HTHREADS, 0, stream>>>(A, gH);
    radix_rowscan<<<BINS, 64, 0, stream>>>(gH);
    radix_scatter<48, false><<<NBLK, STHREADS, 0, stream>>>(A, B, nullptr, gH);

    // pass 3: bits [56,64) — skewed digit; slim payload-only writes in selected range
    radix_hist_s<24><<<NBLK, HTHREADS, 0, stream>>>(B, gH);
    radix_rowscan<<<BINS, 64, 0, stream>>>(gH);
    radix_scatter<56, true><<<NBLK, STHREADS, 0, stream>>>(B, nullptr, (uint32_t*)A, gH);

    finalize<<<(G_CNT + 255) / 256, 256, 0, stream>>>((const uint32_t*)A, td, mxtab, out);
}